// Round 1
// baseline (372.079 us; speedup 1.0000x reference)
//
#include <hip/hip_runtime.h>

#define BB 2
#define SS 2048
#define EE 2048
#define HH 16
#define DD 128
#define SE (3 * EE)  // QKV row stride

typedef __bf16 bf16x8 __attribute__((ext_vector_type(8)));
typedef unsigned short u16x8 __attribute__((ext_vector_type(8)));
typedef float f32x4 __attribute__((ext_vector_type(4)));

__device__ __forceinline__ unsigned short f32_to_bf16(float f) {
  unsigned int u = __builtin_bit_cast(unsigned int, f);
  u += 0x7FFFu + ((u >> 16) & 1u);  // RNE
  return (unsigned short)(u >> 16);
}

__device__ __forceinline__ void gll16(const void* g, const void* lds) {
  __builtin_amdgcn_global_load_lds(
      (const __attribute__((address_space(1))) unsigned int*)g,
      (__attribute__((address_space(3))) unsigned int*)lds, 16, 0, 0);
}

__device__ __forceinline__ bf16x8 lds_frag(const unsigned short* p) {
  return __builtin_bit_cast(bf16x8, *(const u16x8*)p);
}

// ---------------- cast x: fp32 -> bf16 ----------------
__global__ void k_cast_bf16(const float* __restrict__ x, unsigned short* __restrict__ y) {
  int i = blockIdx.x * 256 + threadIdx.x;
  float4 v = ((const float4*)x)[i];
  ushort4 o;
  o.x = f32_to_bf16(v.x); o.y = f32_to_bf16(v.y);
  o.z = f32_to_bf16(v.z); o.w = f32_to_bf16(v.w);
  ((ushort4*)y)[i] = o;
}

// ---- all four W [E,E] fp32 -> Wt [E,E] bf16 (transposed), z selects ----
__global__ void k_transpose_w4(const float* __restrict__ W0, const float* __restrict__ W1,
                               const float* __restrict__ W2, const float* __restrict__ W3,
                               unsigned short* __restrict__ WtBase) {
  const float* W = blockIdx.z == 0 ? W0 : blockIdx.z == 1 ? W1 : blockIdx.z == 2 ? W2 : W3;
  unsigned short* Wt = WtBase + (size_t)blockIdx.z * EE * EE;
  __shared__ float tile[32][33];
  int n0 = blockIdx.x * 32, k0 = blockIdx.y * 32;
  int t = threadIdx.x, r = t >> 5, c = t & 31;
  for (int i = 0; i < 32; i += 8)
    tile[r + i][c] = W[(size_t)(k0 + r + i) * EE + n0 + c];
  __syncthreads();
  for (int i = 0; i < 32; i += 8)
    Wt[(size_t)(n0 + r + i) * EE + k0 + c] = f32_to_bf16(tile[c][r + i]);
}

// ---- per-head transpose: QKV[b*S+s][2E + h*D+d] -> Vt[(bh*D+d)*S+s] ----
__global__ void k_transpose_v(const unsigned short* __restrict__ QKV, unsigned short* __restrict__ Vt) {
  __shared__ unsigned short tile[32][33];
  int s0 = blockIdx.x * 32, d0 = blockIdx.y * 32, bh = blockIdx.z;
  int b = bh >> 4, h = bh & 15;
  int t = threadIdx.x, r = t >> 5, c = t & 31;
  for (int i = 0; i < 32; i += 8)
    tile[r + i][c] = QKV[(size_t)(b * SS + s0 + r + i) * SE + 2 * EE + h * DD + d0 + c];
  __syncthreads();
  for (int i = 0; i < 32; i += 8)
    Vt[(size_t)(bh * DD + d0 + r + i) * SS + s0 + c] = tile[c][r + i];
}

// ---------------- GEMM: C[M,N] = A[M,K] @ Bt[N,K]^T -------------------
// 256x128 tile, BK=64, 8 waves (4Mx2N, 64x64 per wave), triple-buffered LDS
// (144 KB), prefetch distance 2 K-tiles via global_load_lds with counted
// s_waitcnt vmcnt(6) (T3+T4), 2 phases/K-tile of {8 ds_read_b128 || 3 gll16
// -> barrier -> setprio(1) -> 16 MFMA -> setprio(0) -> barrier} (T5).
// Chunk-XOR swizzle (slot = chunk ^ (row&7)) carried over: measured 0 bank
// conflicts in the previous structure; read side uses the same involution.
#define GBM 256
#define GBN 128
#define GBK 64
#define NBUF 3

template <int OUTF32>
__global__ __launch_bounds__(512, 2) void k_gemm_bt8(
    const unsigned short* __restrict__ A, const unsigned short* __restrict__ Bt,
    void* __restrict__ Cout, const float* __restrict__ bias, int K, int N) {
  __shared__ unsigned short As[NBUF * GBM * GBK];  // 96 KB
  __shared__ unsigned short Bs[NBUF * GBN * GBK];  // 48 KB
  const int tid = threadIdx.x;
  const int l = tid & 63, w = tid >> 6;
  const int wr = w >> 1, wc = w & 1;              // 4M x 2N wave grid
  const int m0 = blockIdx.y * GBM, n0 = blockIdx.x * GBN;
  const int tm = l & 15, qc = l >> 4;
  const int swz = tm & 7;
  f32x4 acc[4][4] = {};

  // per-thread staging units: A = 4x16B, B = 2x16B per K-tile
  const unsigned short* srcA[4];
  const unsigned short* srcB[2];
  int ldsA[4], ldsB[2];
  for (int u = 0; u < 4; ++u) {
    int idx = u * 512 + tid;
    int row = idx >> 3, c = (idx & 7) ^ (row & 7);
    srcA[u] = A + (size_t)(m0 + row) * K + c * 8;
    ldsA[u] = idx * 16;
  }
  for (int u = 0; u < 2; ++u) {
    int idx = u * 512 + tid;
    int row = idx >> 3, c = (idx & 7) ^ (row & 7);
    srcB[u] = Bt + (size_t)(n0 + row) * K + c * 8;
    ldsB[u] = idx * 16;
  }

  const int NT = K >> 6;

  // prologue: stage tiles 0 and 1 (12 loads/thread in flight)
  for (int tt = 0; tt < 2; ++tt) {
    char* Ad = (char*)As + tt * (GBM * GBK * 2);
    char* Bd = (char*)Bs + tt * (GBN * GBK * 2);
    const int k0 = tt * GBK;
    for (int u = 0; u < 4; ++u) gll16(srcA[u] + k0, Ad + ldsA[u]);
    for (int u = 0; u < 2; ++u) gll16(srcB[u] + k0, Bd + ldsB[u]);
  }
  asm volatile("s_waitcnt vmcnt(6)" ::: "memory");  // tile 0 landed, tile 1 in flight
  __builtin_amdgcn_s_barrier();

  int cur = 0;
  for (int t = 0; t < NT; ++t) {
    const unsigned short* Ab = As + cur * (GBM * GBK);
    const unsigned short* Bb = Bs + cur * (GBN * GBK);
    int nxt = cur - 1; if (nxt < 0) nxt = NBUF - 1;  // (cur+2)%3
    char* And = (char*)As + nxt * (GBM * GBK * 2);
    char* Bnd = (char*)Bs + nxt * (GBN * GBK * 2);
    const bool pf = (t + 2 < NT);
    const int kpf = (t + 2) * GBK;

    // ---- phase A (K-half 0)
    bf16x8 a0[4], b0[4];
    for (int im = 0; im < 4; ++im)
      a0[im] = lds_frag(&Ab[(wr * 64 + im * 16 + tm) * 64 + ((qc ^ swz) << 3)]);
    for (int in = 0; in < 4; ++in)
      b0[in] = lds_frag(&Bb[(wc * 64 + in * 16 + tm) * 64 + ((qc ^ swz) << 3)]);
    if (pf) {
      gll16(srcA[0] + kpf, And + ldsA[0]);
      gll16(srcA[1] + kpf, And + ldsA[1]);
      gll16(srcB[0] + kpf, Bnd + ldsB[0]);
    }
    __builtin_amdgcn_s_barrier();
    __builtin_amdgcn_s_setprio(1);
    for (int im = 0; im < 4; ++im)
      for (int in = 0; in < 4; ++in)
        acc[im][in] = __builtin_amdgcn_mfma_f32_16x16x32_bf16(a0[im], b0[in], acc[im][in], 0, 0, 0);
    __builtin_amdgcn_s_setprio(0);
    __builtin_amdgcn_s_barrier();

    // ---- phase B (K-half 1)
    bf16x8 a1[4], b1[4];
    for (int im = 0; im < 4; ++im)
      a1[im] = lds_frag(&Ab[(wr * 64 + im * 16 + tm) * 64 + (((4 + qc) ^ swz) << 3)]);
    for (int in = 0; in < 4; ++in)
      b1[in] = lds_frag(&Bb[(wc * 64 + in * 16 + tm) * 64 + (((4 + qc) ^ swz) << 3)]);
    if (pf) {
      gll16(srcA[2] + kpf, And + ldsA[2]);
      gll16(srcA[3] + kpf, And + ldsA[3]);
      gll16(srcB[1] + kpf, Bnd + ldsB[1]);
    }
    __builtin_amdgcn_s_barrier();
    __builtin_amdgcn_s_setprio(1);
    for (int im = 0; im < 4; ++im)
      for (int in = 0; in < 4; ++in)
        acc[im][in] = __builtin_amdgcn_mfma_f32_16x16x32_bf16(a1[im], b1[in], acc[im][in], 0, 0, 0);
    __builtin_amdgcn_s_setprio(0);
    if (t + 1 < NT) {
      // counted drain: next tile's loads complete, tile t+2's (if issued) stay in flight
      if (pf) asm volatile("s_waitcnt vmcnt(6)" ::: "memory");
      else    asm volatile("s_waitcnt vmcnt(0)" ::: "memory");
      __builtin_amdgcn_s_barrier();
    }
    cur = nxt == 0 ? (NBUF - 1) : (nxt - 1);  // cur = (cur+1)%3
    cur = (t + 1) % NBUF;                     // keep it simple & correct
  }

  for (int im = 0; im < 4; ++im)
    for (int in = 0; in < 4; ++in)
      for (int r = 0; r < 4; ++r) {
        int row = m0 + wr * 64 + im * 16 + qc * 4 + r;
        int col = n0 + wc * 64 + in * 16 + tm;
        if (OUTF32)
          ((float*)Cout)[(size_t)row * N + col] = acc[im][in][r] + bias[col];
        else
          ((unsigned short*)Cout)[(size_t)row * N + col] = f32_to_bf16(acc[im][in][r]);
      }
}

// ---------------- flash-style causal attention with ALiBi (unchanged) ----
__global__ __launch_bounds__(256, 2) void k_attn(
    const unsigned short* __restrict__ QKV, const unsigned short* __restrict__ Vt,
    unsigned short* __restrict__ ctx) {
  __shared__ unsigned short smem[40960];  // 80 KB
  const int tid = threadIdx.x;
  const int l = tid & 63, w = tid >> 6;
  const int tm = l & 15, qc = l >> 4;
  const int bh = blockIdx.x, b = bh >> 4, h = bh & 15;
  const int rank = blockIdx.y;
  const int t = (rank < 8) ? (15 - rank) : (rank - 8);
  const int q0 = t * 128;
  const int n_it = 2 * t + 2;
  const float c1 = 0.12751676f;  // log2(e)/sqrt(128)
  const float slopeL = exp2f(-0.5f * (float)(h + 1)) * c1;

  const unsigned short* Qg = QKV + h * DD;
  const unsigned short* Kg = QKV + EE + h * DD;
  const unsigned short* Vg = Vt + (size_t)bh * DD * SS;
  unsigned short* Ps = smem + 32768 + w * 2048;

  for (int is = 0; is < 8; ++is) {
    int idx = (w * 8 + is) * 64 + l;
    int row = idx >> 4, c = (idx & 15) ^ (row & 7);
    gll16(&Qg[(size_t)(b * SS + q0 + row) * SE + c * 8], ((char*)smem) + 32768 + idx * 16);
  }
  for (int is = 0; is < 4; ++is) {
    int idx = (w * 4 + is) * 64 + l;
    int kr = idx >> 4, kc = (idx & 15) ^ (kr & 7);
    gll16(&Kg[(size_t)(b * SS + kr) * SE + kc * 8], ((char*)smem) + idx * 16);
    int vr = idx >> 3, vc = (idx & 7) ^ (vr & 7);
    gll16(&Vg[(size_t)vr * SS + vc * 8], ((char*)smem) + 16384 + idx * 16);
  }
  __syncthreads();
  bf16x8 qf[2][4];
  for (int im = 0; im < 2; ++im)
    for (int kk = 0; kk < 4; ++kk) {
      int row = w * 32 + im * 16 + tm;
      qf[im][kk] = lds_frag(&smem[16384 + (row * 16 + ((kk * 4 + qc) ^ (tm & 7))) * 8]);
    }
  __syncthreads();

  float lr[2][4] = {};
  f32x4 o[2][8] = {};

  for (int it = 0; it < n_it; ++it) {
    const int kt = it * 64;
    const unsigned short* K_ = smem + (it & 1) * 16384;
    const unsigned short* V_ = K_ + 8192;
    if (it + 1 < n_it) {
      char* Kd = ((char*)smem) + ((it + 1) & 1) * 32768;
      int ktn = kt + 64;
      for (int is = 0; is < 4; ++is) {
        int idx = (w * 4 + is) * 64 + l;
        int kr = idx >> 4, kc = (idx & 15) ^ (kr & 7);
        gll16(&Kg[(size_t)(b * SS + ktn + kr) * SE + kc * 8], Kd + idx * 16);
        int vr = idx >> 3, vc = (idx & 7) ^ (vr & 7);
        gll16(&Vg[(size_t)vr * SS + ktn + vc * 8], Kd + 16384 + idx * 16);
      }
    }
    const bool full = (kt + 64 <= q0);

    for (int kn = 0; kn < 4; ++kn) {
      bf16x8 kf[4];
      for (int kk = 0; kk < 4; ++kk) {
        int row = kn * 16 + tm;
        kf[kk] = lds_frag(&K_[(row * 16 + ((kk * 4 + qc) ^ (tm & 7))) * 8]);
      }
      f32x4 a0 = {}, a1 = {};
      for (int kk = 0; kk < 4; ++kk) {
        a0 = __builtin_amdgcn_mfma_f32_16x16x32_bf16(qf[0][kk], kf[kk], a0, 0, 0, 0);
        a1 = __builtin_amdgcn_mfma_f32_16x16x32_bf16(qf[1][kk], kf[kk], a1, 0, 0, 0);
      }
      const int j = kt + kn * 16 + tm;
      for (int im = 0; im < 2; ++im) {
        const f32x4 av = im ? a1 : a0;
        const int ibase = q0 + w * 32 + im * 16 + qc * 4;
        for (int r = 0; r < 4; ++r) {
          int d = j - (ibase + r);
          float arg = av[r] * c1 + slopeL * (float)d;
          if (!full && d > 0) arg = -1e30f;
          float p = __builtin_amdgcn_exp2f(arg);
          lr[im][r] += p;
          unsigned int u = __builtin_bit_cast(unsigned int, p);
          int prow = im * 16 + qc * 4 + r;
          int pslot = (kn * 2 + (tm >> 3)) ^ (prow & 7);
          Ps[(prow * 8 + pslot) * 8 + (tm & 7)] = (unsigned short)(u >> 16);
        }
      }
    }
    asm volatile("s_waitcnt lgkmcnt(0)" ::: "memory");
    bf16x8 pf[2][2];
    for (int im = 0; im < 2; ++im)
      for (int k2 = 0; k2 < 2; ++k2) {
        int prow = im * 16 + tm;
        pf[im][k2] = lds_frag(&Ps[(prow * 8 + ((k2 * 4 + qc) ^ (tm & 7))) * 8]);
      }
    for (int dc = 0; dc < 8; ++dc) {
      int vrow = dc * 16 + tm;
      bf16x8 vf0 = lds_frag(&V_[(vrow * 8 + (qc ^ (tm & 7))) * 8]);
      bf16x8 vf1 = lds_frag(&V_[(vrow * 8 + ((4 + qc) ^ (tm & 7))) * 8]);
      o[0][dc] = __builtin_amdgcn_mfma_f32_16x16x32_bf16(pf[0][0], vf0, o[0][dc], 0, 0, 0);
      o[0][dc] = __builtin_amdgcn_mfma_f32_16x16x32_bf16(pf[0][1], vf1, o[0][dc], 0, 0, 0);
      o[1][dc] = __builtin_amdgcn_mfma_f32_16x16x32_bf16(pf[1][0], vf0, o[1][dc], 0, 0, 0);
      o[1][dc] = __builtin_amdgcn_mfma_f32_16x16x32_bf16(pf[1][1], vf1, o[1][dc], 0, 0, 0);
    }
    __syncthreads();
  }

  for (int im = 0; im < 2; ++im)
    for (int r = 0; r < 4; ++r) {
      float s = lr[im][r];
      for (int off = 8; off >= 1; off >>= 1) s += __shfl_xor(s, off, 64);
      float inv = 1.0f / s;
      int i = q0 + w * 32 + im * 16 + qc * 4 + r;
      for (int dc = 0; dc < 8; ++dc)
        ctx[(size_t)(b * SS + i) * EE + h * DD + dc * 16 + tm] =
            f32_to_bf16(o[im][dc][r] * inv);
    }
}

extern "C" void kernel_launch(void* const* d_in, const int* in_sizes, int n_in,
                              void* d_out, int out_size, void* d_ws, size_t ws_size,
                              hipStream_t stream) {
  const float* x  = (const float*)d_in[0];
  const float* Wq = (const float*)d_in[1];
  const float* Wk = (const float*)d_in[2];
  const float* Wv = (const float*)d_in[3];
  const float* Wo = (const float*)d_in[4];
  const float* bo = (const float*)d_in[5];
  float* out = (float*)d_out;

  const size_t XE = (size_t)BB * SS * EE;
  const size_t WE = (size_t)EE * EE;
  unsigned short* ws   = (unsigned short*)d_ws;
  unsigned short* xb   = ws;            // reused as ctx
  unsigned short* WqT  = xb + XE;       // WqT|WkT|WvT|WoT contiguous
  unsigned short* WoT  = WqT + 3 * WE;
  unsigned short* QKVb = WoT + WE;      // [B*S][3E]
  unsigned short* Vt   = QKVb + 3 * XE;
  unsigned short* ctx  = xb;

  k_cast_bf16<<<XE / 1024, 256, 0, stream>>>(x, xb);
  k_transpose_w4<<<dim3(EE / 32, EE / 32, 4), 256, 0, stream>>>(Wq, Wk, Wv, Wo, WqT);

  dim3 gqkv(SE / GBN, (BB * SS) / GBM);  // (48, 16) = 768 blocks = 3 exact rounds
  k_gemm_bt8<0><<<gqkv, 512, 0, stream>>>(xb, WqT, QKVb, nullptr, EE, SE);

  k_transpose_v<<<dim3(SS / 32, DD / 32, BB * HH), 256, 0, stream>>>(QKVb, Vt);
  k_attn<<<dim3(BB * HH, SS / 128), 256, 0, stream>>>(QKVb, Vt, ctx);

  dim3 gg(EE / GBN, (BB * SS) / GBM);  // (16, 16) = 256 blocks = 1 exact round
  k_gemm_bt8<1><<<gg, 512, 0, stream>>>(ctx, WoT, out, bo, EE, EE);
}